// Round 2
// baseline (106.448 us; speedup 1.0000x reference)
//
#include <hip/hip_runtime.h>
#include <math.h>

#define THRESH 0.65f

// ws layout (float offsets):
// cellscore: [0, 8192)      32 maps x 256 cells
// cellidx:   [8192, 16384)  (int)
// bgval:     [16384, 16896) 32 maps x 16 stripe partials
// bgidx:     [16896, 17408) (int)

// K1: grid (16 cellrows, 16 map-pairs) x 256 threads.
// Each block: maps {2*by, 2*by+1}, cell row cy = bx (16 cells = 64 output rows).
// Computes the 6 needed sim rows (incl. halo, clamped) from feat directly,
// then bilinear-upsample scan: per-cell argmax + stripe-wide argmin.
__global__ __launch_bounds__(256) void k_main(const float* __restrict__ feat,
                                              const float* __restrict__ ref,
                                              float* __restrict__ cellscore,
                                              int* __restrict__ cellidx,
                                              float* __restrict__ bgval,
                                              int* __restrict__ bgidx) {
    __shared__ float rn[2][256];   // normalized ref rows for the 2 maps
    __shared__ float S[2][384];    // 6 sim rows x 64 cols per map
    __shared__ float red[256];
    __shared__ float wmin[4];
    __shared__ int wmini[4];

    int t = threadIdx.x;
    int cy = blockIdx.x;
    int m0 = blockIdx.y * 2;

    // --- ref L2-normalize (2 maps) ---
    for (int mi = 0; mi < 2; ++mi) {
        float v = ref[(m0 + mi) * 256 + t];
        red[t] = v * v;
        __syncthreads();
        for (int s = 128; s > 0; s >>= 1) {
            if (t < s) red[t] += red[t + s];
            __syncthreads();
        }
        float den = sqrtf(red[0]) + 1e-12f;
        __syncthreads();  // everyone read red[0] before reuse
        rn[mi][t] = v / den;
    }
    __syncthreads();

    // --- sim for 6 rows (with halo), both maps, feat loaded once ---
    int ybase = 4 * cy - 1;
    for (int slot = t; slot < 384; slot += 256) {
        int j = slot >> 6, col = slot & 63;
        int gy = min(max(ybase + j, 0), 63);
        const float* fp = feat + gy * 64 + col;
        float dot0 = 0.f, dot1 = 0.f, nsq = 0.f;
        for (int g = 0; g < 16; ++g) {
            float p0 = 0.f, p1 = 0.f, nq = 0.f;
#pragma unroll
            for (int cc = 0; cc < 16; ++cc) {
                int c = g * 16 + cc;
                float v = fp[c * 4096];
                p0 += v * rn[0][c];
                p1 += v * rn[1][c];
                nq += v * v;
            }
            dot0 += p0; dot1 += p1; nsq += nq;
        }
        float den = sqrtf(nsq) + 1e-12f;
        S[0][slot] = dot0 / den;
        S[1][slot] = dot1 / den;
    }
    __syncthreads();

    // --- bilinear upsample scan: thread = (cell cx = t>>4, subrow r = t&15) ---
    int cx = t >> 4, r = t & 15;
    int xbase = 4 * cx - 1;
    const int lstart[5] = {0, 8, 24, 40, 56};
    const int lend[5]   = {8, 24, 40, 56, 64};

    for (int mi = 0; mi < 2; ++mi) {
        const float* Sm = S[mi];
        float bmax = -1e30f; int bmaxi = 0;
        float bmin = 1e30f;  int bmini = 0;
        for (int rr = 0; rr < 4; ++rr) {
            int lyy = r * 4 + rr;       // local row in cell 0..63
            int oy = cy * 64 + lyy;     // global output row
            float fy = (oy + 0.5f) * 0.0625f - 0.5f;  // exact dyadic
            float y0f = floorf(fy);
            int y0 = (int)y0f;
            float wy = fy - y0f;
            bool ylo = fy < 0.0f, yhi = fy > 63.0f;
            int py0 = min(max(y0, 0), 63) - ybase;      // 0..5
            int py1 = min(max(y0 + 1, 0), 63) - ybase;  // 0..5
            const float* P0 = Sm + py0 * 64;
            const float* P1 = Sm + py1 * 64;
            float w1y = 1.0f - wy;
#pragma unroll
            for (int s5 = 0; s5 < 5; ++s5) {
                int x0 = xbase + s5;
                int c0 = min(max(x0, 0), 63);
                int c1 = min(max(x0 + 1, 0), 63);
                float a = P0[c0], b = P0[c1];
                float c = P1[c0], d = P1[c1];
                // y-combine first (mirrors reference), exact edge passthrough
                float q0 = ylo ? a : (yhi ? c : w1y * a + wy * c);
                float q1 = ylo ? b : (yhi ? d : w1y * b + wy * d);
                float x0f = (float)x0;
                for (int l = lstart[s5]; l < lend[s5]; ++l) {
                    int ox = cx * 64 + l;
                    float fx = (ox + 0.5f) * 0.0625f - 0.5f;
                    float wx = fx - x0f;
                    float v;
                    if (fx < 0.0f)        v = q1;  // single tap at col 0
                    else if (fx > 63.0f)  v = q0;  // single tap at col 63
                    else                  v = (1.0f - wx) * q0 + wx * q1;
                    int li = lyy * 64 + l;
                    if (v > bmax) { bmax = v; bmaxi = li; }
                    if (v < bmin) { bmin = v; bmini = oy * 1024 + ox; }
                }
            }
        }
        // per-cell argmax reduce over the 16 subrow-threads (width-16 shuffle);
        // lower li wins ties -> global first-occurrence semantics
        for (int off = 8; off > 0; off >>= 1) {
            float ov = __shfl_down(bmax, off, 16);
            int   oi = __shfl_down(bmaxi, off, 16);
            if (ov > bmax || (ov == bmax && oi < bmaxi)) { bmax = ov; bmaxi = oi; }
        }
        if (r == 0) {
            int cell = cy * 16 + cx;
            cellscore[(m0 + mi) * 256 + cell] = bmax;
            cellidx[(m0 + mi) * 256 + cell] = bmaxi;
        }
        // stripe-wide bg min: wave reduce then cross-wave via LDS
        for (int off = 32; off > 0; off >>= 1) {
            float mv = __shfl_down(bmin, off);
            int   mj = __shfl_down(bmini, off);
            if (mv < bmin || (mv == bmin && mj < bmini)) { bmin = mv; bmini = mj; }
        }
        int wid = t >> 6;
        if ((t & 63) == 0) { wmin[wid] = bmin; wmini[wid] = bmini; }
        __syncthreads();
        if (t == 0) {
            float bv = wmin[0]; int bi = wmini[0];
            for (int w = 1; w < 4; ++w) {
                if (wmin[w] < bv || (wmin[w] == bv && wmini[w] < bi)) {
                    bv = wmin[w]; bi = wmini[w];
                }
            }
            bgval[(m0 + mi) * 16 + cy] = bv;
            bgidx[(m0 + mi) * 16 + cy] = bi;
        }
        __syncthreads();  // wmin reuse on next map
    }
}

// K2: 32 blocks (one per map) x 256 threads (one per cell):
// threshold + stable descending rank-sort + bg merge over 16 stripe partials.
__global__ __launch_bounds__(256) void k_out(const float* __restrict__ cellscore,
                                             const int* __restrict__ cellidx,
                                             const float* __restrict__ bgval,
                                             const int* __restrict__ bgidx,
                                             float* __restrict__ out) {
    __shared__ float sc[256];
    int m = blockIdx.x, t = threadIdx.x;
    float score = cellscore[m * 256 + t];
    int li = cellidx[m * 256 + t];
    int cy = t >> 4, cx = t & 15;
    int ly = li >> 6, lx = li & 63;
    bool valid = score > THRESH;
    float px = valid ? (float)(cx * 64 + lx) : -1.0f;
    float py = valid ? (float)(cy * 64 + ly) : -1.0f;
    float ps = valid ? score : -1.0f;
    sc[t] = ps;
    __syncthreads();
    // stable descending rank: key (-score, cell_id)
    int rank = 0;
    for (int j = 0; j < 256; ++j) {
        float sj = sc[j];
        rank += (sj > ps || (sj == ps && j < t)) ? 1 : 0;
    }
    float* o = out + m * 768 + rank * 3;
    o[0] = px; o[1] = py; o[2] = ps;
    // bg: lexicographic min (val, flat idx) over 16 stripe partials
    if (t == 0) {
        float bv = bgval[m * 16]; int bi = bgidx[m * 16];
        for (int w = 1; w < 16; ++w) {
            float v = bgval[m * 16 + w]; int i2 = bgidx[m * 16 + w];
            if (v < bv || (v == bv && i2 < bi)) { bv = v; bi = i2; }
        }
        out[24576 + m * 2 + 0] = (float)(bi % 1024);  // x = col
        out[24576 + m * 2 + 1] = (float)(bi / 1024);  // y = row
    }
}

extern "C" void kernel_launch(void* const* d_in, const int* in_sizes, int n_in,
                              void* d_out, int out_size, void* d_ws, size_t ws_size,
                              hipStream_t stream) {
    const float* feat = (const float*)d_in[0];  // (1,256,64,64)
    const float* ref  = (const float*)d_in[1];  // (32,1,256)
    if (in_sizes[0] == 32 * 256) {  // defensive: swap if order reversed
        feat = (const float*)d_in[1];
        ref  = (const float*)d_in[0];
    }
    float* out = (float*)d_out;
    float* ws = (float*)d_ws;
    float* cellscore = ws;
    int*   cellidx   = (int*)(ws + 8192);
    float* bgval     = ws + 16384;
    int*   bgidx     = (int*)(ws + 16896);

    k_main<<<dim3(16, 16), 256, 0, stream>>>(feat, ref, cellscore, cellidx, bgval, bgidx);
    k_out<<<32, 256, 0, stream>>>(cellscore, cellidx, bgval, bgidx, out);
}